// Round 1
// baseline (819.791 us; speedup 1.0000x reference)
//
#include <hip/hip_runtime.h>
#include <hip/hip_bf16.h>

// ---------------- helpers ----------------
__device__ __forceinline__ unsigned short f2bf(float f) {
    __hip_bfloat16 h = __float2bfloat16(f);
    union { __hip_bfloat16 h; unsigned short u; } cv; cv.h = h; return cv.u;
}
__device__ __forceinline__ float bf2f(unsigned short u) {
    unsigned int b = ((unsigned int)u) << 16;
    union { unsigned int u; float f; } cv; cv.u = b; return cv.f;
}

// ---------------- 1. degree count (real edges only; +1 self added later) ----
__global__ void k_count(const int* __restrict__ e0, const int* __restrict__ e1,
                        const int* __restrict__ e2, int E, int N, int* cnt) {
    const int* ep = blockIdx.y == 0 ? e0 : (blockIdx.y == 1 ? e1 : e2);
    int i = blockIdx.x * blockDim.x + threadIdx.x;
    if (i < E) {
        int dst = ep[E + i];
        atomicAdd(&cnt[blockIdx.y * N + dst], 1);
    }
}

// ---------------- 2. hierarchical exclusive scan ----------------
__global__ void k_scan1(const int* __restrict__ cnt, int* row_start, int* bsums, int N) {
    __shared__ int s[1024];
    int t = threadIdx.x;
    int base = blockIdx.y * N;
    int i = blockIdx.x * 1024 + t;
    int v = (i < N) ? cnt[base + i] : 0;
    s[t] = v; __syncthreads();
    for (int off = 1; off < 1024; off <<= 1) {
        int add = (t >= off) ? s[t - off] : 0;
        __syncthreads();
        s[t] += add;
        __syncthreads();
    }
    int incl = s[t];
    if (i < N) row_start[base + i] = incl - v;     // block-local exclusive
    if (t == 1023) bsums[blockIdx.y * 1024 + blockIdx.x] = incl;  // block total
}

__global__ void k_scan2(int* bsums, int nb) {
    __shared__ int s[128];
    int t = threadIdx.x;  // 128 threads
    int v = (t < nb) ? bsums[blockIdx.y * 1024 + t] : 0;
    s[t] = v; __syncthreads();
    for (int off = 1; off < 128; off <<= 1) {
        int add = (t >= off) ? s[t - off] : 0;
        __syncthreads();
        s[t] += add;
        __syncthreads();
    }
    if (t < nb) bsums[blockIdx.y * 1024 + t] = s[t] - v;  // exclusive over blocks
}

__global__ void k_scan3(int* row_start, int* cursor, const int* __restrict__ bsums, int N) {
    int base = blockIdx.y * N;
    int i = blockIdx.x * 1024 + threadIdx.x;
    if (i < N) {
        int v = row_start[base + i] + bsums[blockIdx.y * 1024 + blockIdx.x];
        row_start[base + i] = v;
        cursor[base + i]    = v;
    }
}

// ---------------- 3. CSR fill (1 atomic per edge) ----------------
__global__ void k_fill(const int* __restrict__ e0, const int* __restrict__ e1,
                       const int* __restrict__ e2, int E, int N,
                       int* cursor, int* __restrict__ sorted) {
    const int* ep = blockIdx.y == 0 ? e0 : (blockIdx.y == 1 ? e1 : e2);
    int i = blockIdx.x * blockDim.x + threadIdx.x;
    if (i < E) {
        int src = ep[i];
        int dst = ep[E + i];
        int pos = atomicAdd(&cursor[blockIdx.y * N + dst], 1);
        sorted[(size_t)blockIdx.y * E + pos] = src;
    }
}

// ---------------- 4. fused 4-matrix GEMM ----------------
// out0 = x@W_ln + b_ln  (fp32 -> d_out)
// g_m  = (x@W_m) * dinv_m[row]  (bf16 -> ws), m = 1..3
#define GSTEP(XK, KC)                                                              \
    do {                                                                           \
        const float xk_ = (XK);                                                    \
        float4 w_;                                                                 \
        w_ = *(const float4*)(Wbase + 0 * 4096 + (KC) * 64);                       \
        a0.x += xk_ * w_.x; a0.y += xk_ * w_.y; a0.z += xk_ * w_.z; a0.w += xk_ * w_.w; \
        w_ = *(const float4*)(Wbase + 1 * 4096 + (KC) * 64);                       \
        a1.x += xk_ * w_.x; a1.y += xk_ * w_.y; a1.z += xk_ * w_.z; a1.w += xk_ * w_.w; \
        w_ = *(const float4*)(Wbase + 2 * 4096 + (KC) * 64);                       \
        a2.x += xk_ * w_.x; a2.y += xk_ * w_.y; a2.z += xk_ * w_.z; a2.w += xk_ * w_.w; \
        w_ = *(const float4*)(Wbase + 3 * 4096 + (KC) * 64);                       \
        a3.x += xk_ * w_.x; a3.y += xk_ * w_.y; a3.z += xk_ * w_.z; a3.w += xk_ * w_.w; \
    } while (0)

__global__ __launch_bounds__(256) void k_gemm(
    const float* __restrict__ x,
    const float* __restrict__ Wln, const float* __restrict__ bln,
    const float* __restrict__ W1, const float* __restrict__ W2,
    const float* __restrict__ W3,
    const int* __restrict__ cnt, int N,
    float* __restrict__ out0, unsigned short* __restrict__ g) {
    __shared__ float Wl[4 * 4096];
    int t = threadIdx.x;
    const float* Ws[4] = {Wln, W1, W2, W3};
    #pragma unroll
    for (int m = 0; m < 4; m++)
        for (int i = t; i < 4096; i += 256) Wl[m * 4096 + i] = Ws[m][i];
    __syncthreads();

    int r = blockIdx.x * 256 + t;
    if (r >= N) return;

    float4 xv[16];
    const float4* xr = (const float4*)(x + (size_t)r * 64);
    #pragma unroll
    for (int i = 0; i < 16; i++) xv[i] = xr[i];

    float dinv0 = rsqrtf((float)(cnt[0 * N + r] + 1));
    float dinv1 = rsqrtf((float)(cnt[1 * N + r] + 1));
    float dinv2 = rsqrtf((float)(cnt[2 * N + r] + 1));

    const size_t NB = (size_t)N * 64;
    float* orow = out0 + (size_t)r * 64;
    unsigned short* g0 = g + 0 * NB + (size_t)r * 64;
    unsigned short* g1 = g + 1 * NB + (size_t)r * 64;
    unsigned short* g2 = g + 2 * NB + (size_t)r * 64;

    for (int j4 = 0; j4 < 16; j4++) {
        float4 a0 = make_float4(0.f, 0.f, 0.f, 0.f), a1 = a0, a2 = a0, a3 = a0;
        const float* Wbase = Wl + j4 * 4;
        #pragma unroll
        for (int k4 = 0; k4 < 16; k4++) {
            const float4 xk4 = xv[k4];
            GSTEP(xk4.x, k4 * 4 + 0);
            GSTEP(xk4.y, k4 * 4 + 1);
            GSTEP(xk4.z, k4 * 4 + 2);
            GSTEP(xk4.w, k4 * 4 + 3);
        }
        float4 bl = ((const float4*)bln)[j4];
        float4 o = make_float4(a0.x + bl.x, a0.y + bl.y, a0.z + bl.z, a0.w + bl.w);
        ((float4*)orow)[j4] = o;
        ushort4 u;
        u.x = f2bf(a1.x * dinv0); u.y = f2bf(a1.y * dinv0);
        u.z = f2bf(a1.z * dinv0); u.w = f2bf(a1.w * dinv0);
        ((ushort4*)g0)[j4] = u;
        u.x = f2bf(a2.x * dinv1); u.y = f2bf(a2.y * dinv1);
        u.z = f2bf(a2.z * dinv1); u.w = f2bf(a2.w * dinv1);
        ((ushort4*)g1)[j4] = u;
        u.x = f2bf(a3.x * dinv2); u.y = f2bf(a3.y * dinv2);
        u.z = f2bf(a3.z * dinv2); u.w = f2bf(a3.w * dinv2);
        ((ushort4*)g2)[j4] = u;
    }
}

// ---------------- 5. gather + finalize (no atomics) ----------------
// 16 lanes per (node, conv): out[v] = dinv[v] * (g[v] + sum_{u->v} g[u]) + b
__global__ __launch_bounds__(256) void k_gather(
    const unsigned short* __restrict__ g, const int* __restrict__ sorted,
    const int* __restrict__ row_start, const int* __restrict__ cnt,
    const float* __restrict__ b1, const float* __restrict__ b2,
    const float* __restrict__ b3,
    int N, int E, float* __restrict__ out) {
    int t = threadIdx.x;
    int node = blockIdx.x * 16 + (t >> 4);
    int l = t & 15;
    int conv = blockIdx.y;
    if (node >= N) return;

    const size_t NB = (size_t)N * 64;
    const unsigned short* gm = g + (size_t)conv * NB;
    int rs = row_start[conv * N + node];
    int ne = cnt[conv * N + node];
    const int* sp = sorted + (size_t)conv * E + rs;

    ushort4 su = ((const ushort4*)(gm + (size_t)node * 64))[l];
    float4 acc = make_float4(bf2f(su.x), bf2f(su.y), bf2f(su.z), bf2f(su.w));

    for (int j = 0; j < ne; j++) {
        int s = sp[j];
        ushort4 u = ((const ushort4*)(gm + (size_t)s * 64))[l];
        acc.x += bf2f(u.x); acc.y += bf2f(u.y);
        acc.z += bf2f(u.z); acc.w += bf2f(u.w);
    }

    float dv = rsqrtf((float)(ne + 1));
    const float* bp = conv == 0 ? b1 : (conv == 1 ? b2 : b3);
    float4 bb = ((const float4*)bp)[l];
    float4 o = make_float4(acc.x * dv + bb.x, acc.y * dv + bb.y,
                           acc.z * dv + bb.z, acc.w * dv + bb.w);
    ((float4*)(out + (size_t)(1 + conv) * NB + (size_t)node * 64))[l] = o;
}

// ---------------- launch ----------------
extern "C" void kernel_launch(void* const* d_in, const int* in_sizes, int n_in,
                              void* d_out, int out_size, void* d_ws, size_t ws_size,
                              hipStream_t stream) {
    const float* x   = (const float*)d_in[0];
    const int*   e0  = (const int*)d_in[1];
    const int*   e1  = (const int*)d_in[2];
    const int*   e2  = (const int*)d_in[3];
    const float* Wln = (const float*)d_in[4];
    const float* bln = (const float*)d_in[5];
    const float* W1  = (const float*)d_in[6];
    const float* b1  = (const float*)d_in[7];
    const float* W2  = (const float*)d_in[8];
    const float* b2  = (const float*)d_in[9];
    const float* W3  = (const float*)d_in[10];
    const float* b3  = (const float*)d_in[11];

    int N = in_sizes[0] / 64;
    int E = in_sizes[1] / 2;
    float* out = (float*)d_out;

    // workspace carve (256B aligned)
    char* w = (char*)d_ws;
    auto alloc = [&](size_t bytes) {
        char* p = w;
        w += (bytes + 255) / 256 * 256;
        return p;
    };
    unsigned short* g      = (unsigned short*)alloc((size_t)3 * N * 64 * 2);
    int* cnt               = (int*)alloc((size_t)3 * N * 4);
    int* row_start         = (int*)alloc((size_t)3 * N * 4);
    int* cursor            = (int*)alloc((size_t)3 * N * 4);
    int* bsums             = (int*)alloc((size_t)3 * 1024 * 4);
    int* sorted            = (int*)alloc((size_t)3 * E * 4);

    hipMemsetAsync(cnt, 0, (size_t)3 * N * 4, stream);

    dim3 bE(256), gE((E + 255) / 256, 3);
    k_count<<<gE, bE, 0, stream>>>(e0, e1, e2, E, N, cnt);

    int nb = (N + 1023) / 1024;   // 98 for N=100000 (fits the 128-wide scan2)
    k_scan1<<<dim3(nb, 3), 1024, 0, stream>>>(cnt, row_start, bsums, N);
    k_scan2<<<dim3(1, 3), 128, 0, stream>>>(bsums, nb);
    k_scan3<<<dim3(nb, 3), 1024, 0, stream>>>(row_start, cursor, bsums, N);

    k_gemm<<<dim3((N + 255) / 256), 256, 0, stream>>>(x, Wln, bln, W1, W2, W3,
                                                      cnt, N, out, g);
    k_fill<<<gE, bE, 0, stream>>>(e0, e1, e2, E, N, cursor, sorted);
    k_gather<<<dim3((N + 15) / 16, 3), 256, 0, stream>>>(g, sorted, row_start, cnt,
                                                         b1, b2, b3, N, E, out);
}

// Round 2
// 497.498 us; speedup vs baseline: 1.6478x; 1.6478x over previous
//
#include <hip/hip_runtime.h>
#include <hip/hip_bf16.h>

#define NBKT_MAX 512

// ---------------- helpers ----------------
__device__ __forceinline__ unsigned short f2bf(float f) {
    __hip_bfloat16 h = __float2bfloat16(f);
    union { __hip_bfloat16 h; unsigned short u; } cv; cv.h = h; return cv.u;
}
__device__ __forceinline__ float bf2f(unsigned short u) {
    unsigned int b = ((unsigned int)u) << 16;
    union { unsigned int u; float f; } cv; cv.u = b; return cv.f;
}
__device__ __forceinline__ const int* pick(const int* e0, const int* e1, const int* e2, int y) {
    return y == 0 ? e0 : (y == 1 ? e1 : e2);
}

// ---------------- 1. bucket histogram (bucket = dst >> 8) ----------------
__global__ __launch_bounds__(256) void k_hist(const int* __restrict__ e0, const int* __restrict__ e1,
                                              const int* __restrict__ e2, int E, int nbkt,
                                              int* __restrict__ bucket_cnt) {
    const int* ep = pick(e0, e1, e2, blockIdx.y);
    __shared__ int h[NBKT_MAX];
    for (int i = threadIdx.x; i < nbkt; i += 256) h[i] = 0;
    __syncthreads();
    int base = blockIdx.x * 4096;
    #pragma unroll
    for (int k = 0; k < 16; k++) {
        int i = base + k * 256 + threadIdx.x;
        if (i < E) atomicAdd(&h[ep[E + i] >> 8], 1);
    }
    __syncthreads();
    for (int i = threadIdx.x; i < nbkt; i += 256)
        if (h[i]) atomicAdd(&bucket_cnt[blockIdx.y * nbkt + i], h[i]);
}

// ---------------- 2. scan over buckets ----------------
__global__ __launch_bounds__(512) void k_scanb(const int* __restrict__ bucket_cnt,
                                               int* __restrict__ bucket_base,
                                               int* __restrict__ bucket_cursor, int nbkt) {
    __shared__ int s[512];
    int t = threadIdx.x;
    int v = (t < nbkt) ? bucket_cnt[blockIdx.y * nbkt + t] : 0;
    s[t] = v; __syncthreads();
    for (int off = 1; off < 512; off <<= 1) {
        int a = (t >= off) ? s[t - off] : 0;
        __syncthreads();
        s[t] += a;
        __syncthreads();
    }
    if (t < nbkt) {
        int e = s[t] - v;
        bucket_base[blockIdx.y * nbkt + t] = e;
        bucket_cursor[blockIdx.y * nbkt + t] = e;
    }
}

// ---------------- 3. multisplit binning (packed (src<<8)|dst_local) --------
__global__ __launch_bounds__(256) void k_bin(const int* __restrict__ e0, const int* __restrict__ e1,
                                             const int* __restrict__ e2, int E, int nbkt,
                                             int* __restrict__ bucket_cursor,
                                             unsigned int* __restrict__ binned) {
    const int* ep = pick(e0, e1, e2, blockIdx.y);
    __shared__ int h[NBKT_MAX];
    __shared__ int base[NBKT_MAX];
    for (int i = threadIdx.x; i < nbkt; i += 256) h[i] = 0;
    __syncthreads();
    int cbase = blockIdx.x * 8192;
    #pragma unroll
    for (int k = 0; k < 32; k++) {
        int i = cbase + k * 256 + threadIdx.x;
        if (i < E) atomicAdd(&h[ep[E + i] >> 8], 1);
    }
    __syncthreads();
    for (int i = threadIdx.x; i < nbkt; i += 256) {
        int c = h[i];
        base[i] = c ? atomicAdd(&bucket_cursor[blockIdx.y * nbkt + i], c) : 0;
        h[i] = 0;  // reuse as local cursor
    }
    __syncthreads();
    unsigned int* bout = binned + (size_t)blockIdx.y * E;
    #pragma unroll
    for (int k = 0; k < 32; k++) {
        int i = cbase + k * 256 + threadIdx.x;
        if (i < E) {
            int s = ep[i];
            int d = ep[E + i];
            int b = d >> 8;
            int lp = atomicAdd(&h[b], 1);
            bout[base[b] + lp] = ((unsigned)s << 8) | (unsigned)(d & 255);
        }
    }
}

// ---------------- 4. per-bucket count + scan + CSR fill (all in LDS) -------
__global__ __launch_bounds__(256) void k_csr(const unsigned int* __restrict__ binned,
                                             const int* __restrict__ bucket_cnt,
                                             const int* __restrict__ bucket_base,
                                             int E, int N, int nbkt,
                                             int* __restrict__ cnt, int* __restrict__ row_start,
                                             int* __restrict__ sorted) {
    int b = blockIdx.x, conv = blockIdx.y, t = threadIdx.x;
    __shared__ int c[256];
    __shared__ int sc[256];
    int segbase = bucket_base[conv * nbkt + b];
    int segcnt  = bucket_cnt[conv * nbkt + b];
    const unsigned int* bin = binned + (size_t)conv * E + segbase;

    c[t] = 0; __syncthreads();
    for (int i = t; i < segcnt; i += 256) atomicAdd(&c[bin[i] & 255], 1);
    __syncthreads();

    int v = c[t];
    sc[t] = v; __syncthreads();
    for (int off = 1; off < 256; off <<= 1) {
        int a = (t >= off) ? sc[t - off] : 0;
        __syncthreads();
        sc[t] += a;
        __syncthreads();
    }
    int ex = sc[t] - v;
    int node = (b << 8) + t;
    if (node < N) {
        cnt[conv * N + node] = v;
        row_start[conv * N + node] = segbase + ex;
    }
    __syncthreads();
    c[t] = ex;  // per-node cursor
    __syncthreads();
    int* so = sorted + (size_t)conv * E + segbase;
    for (int i = t; i < segcnt; i += 256) {
        unsigned p = bin[i];
        int pos = atomicAdd(&c[p & 255], 1);
        so[pos] = (int)(p >> 8);
    }
}

// ---------------- 5. fused 4-matrix GEMM ----------------
#define GSTEP(XK, KC)                                                              \
    do {                                                                           \
        const float xk_ = (XK);                                                    \
        float4 w_;                                                                 \
        w_ = *(const float4*)(Wbase + 0 * 4096 + (KC) * 64);                       \
        a0.x += xk_ * w_.x; a0.y += xk_ * w_.y; a0.z += xk_ * w_.z; a0.w += xk_ * w_.w; \
        w_ = *(const float4*)(Wbase + 1 * 4096 + (KC) * 64);                       \
        a1.x += xk_ * w_.x; a1.y += xk_ * w_.y; a1.z += xk_ * w_.z; a1.w += xk_ * w_.w; \
        w_ = *(const float4*)(Wbase + 2 * 4096 + (KC) * 64);                       \
        a2.x += xk_ * w_.x; a2.y += xk_ * w_.y; a2.z += xk_ * w_.z; a2.w += xk_ * w_.w; \
        w_ = *(const float4*)(Wbase + 3 * 4096 + (KC) * 64);                       \
        a3.x += xk_ * w_.x; a3.y += xk_ * w_.y; a3.z += xk_ * w_.z; a3.w += xk_ * w_.w; \
    } while (0)

__global__ __launch_bounds__(256) void k_gemm(
    const float* __restrict__ x,
    const float* __restrict__ Wln, const float* __restrict__ bln,
    const float* __restrict__ W1, const float* __restrict__ W2,
    const float* __restrict__ W3,
    const int* __restrict__ cnt, int N,
    float* __restrict__ out0, unsigned short* __restrict__ g) {
    __shared__ float Wl[4 * 4096];
    int t = threadIdx.x;
    const float* Ws[4] = {Wln, W1, W2, W3};
    #pragma unroll
    for (int m = 0; m < 4; m++)
        for (int i = t; i < 4096; i += 256) Wl[m * 4096 + i] = Ws[m][i];
    __syncthreads();

    int r = blockIdx.x * 256 + t;
    if (r >= N) return;

    float4 xv[16];
    const float4* xr = (const float4*)(x + (size_t)r * 64);
    #pragma unroll
    for (int i = 0; i < 16; i++) xv[i] = xr[i];

    float dinv0 = rsqrtf((float)(cnt[0 * N + r] + 1));
    float dinv1 = rsqrtf((float)(cnt[1 * N + r] + 1));
    float dinv2 = rsqrtf((float)(cnt[2 * N + r] + 1));

    const size_t NB = (size_t)N * 64;
    float* orow = out0 + (size_t)r * 64;
    unsigned short* g0 = g + 0 * NB + (size_t)r * 64;
    unsigned short* g1 = g + 1 * NB + (size_t)r * 64;
    unsigned short* g2 = g + 2 * NB + (size_t)r * 64;

    for (int j4 = 0; j4 < 16; j4++) {
        float4 a0 = make_float4(0.f, 0.f, 0.f, 0.f), a1 = a0, a2 = a0, a3 = a0;
        const float* Wbase = Wl + j4 * 4;
        #pragma unroll
        for (int k4 = 0; k4 < 16; k4++) {
            const float4 xk4 = xv[k4];
            GSTEP(xk4.x, k4 * 4 + 0);
            GSTEP(xk4.y, k4 * 4 + 1);
            GSTEP(xk4.z, k4 * 4 + 2);
            GSTEP(xk4.w, k4 * 4 + 3);
        }
        float4 bl = ((const float4*)bln)[j4];
        float4 o = make_float4(a0.x + bl.x, a0.y + bl.y, a0.z + bl.z, a0.w + bl.w);
        ((float4*)orow)[j4] = o;
        ushort4 u;
        u.x = f2bf(a1.x * dinv0); u.y = f2bf(a1.y * dinv0);
        u.z = f2bf(a1.z * dinv0); u.w = f2bf(a1.w * dinv0);
        ((ushort4*)g0)[j4] = u;
        u.x = f2bf(a2.x * dinv1); u.y = f2bf(a2.y * dinv1);
        u.z = f2bf(a2.z * dinv1); u.w = f2bf(a2.w * dinv1);
        ((ushort4*)g1)[j4] = u;
        u.x = f2bf(a3.x * dinv2); u.y = f2bf(a3.y * dinv2);
        u.z = f2bf(a3.z * dinv2); u.w = f2bf(a3.w * dinv2);
        ((ushort4*)g2)[j4] = u;
    }
}

// ---------------- 6. gather + finalize (no atomics) ----------------
__global__ __launch_bounds__(256) void k_gather(
    const unsigned short* __restrict__ g, const int* __restrict__ sorted,
    const int* __restrict__ row_start, const int* __restrict__ cnt,
    const float* __restrict__ b1, const float* __restrict__ b2,
    const float* __restrict__ b3,
    int N, int E, float* __restrict__ out) {
    int t = threadIdx.x;
    int node = blockIdx.x * 16 + (t >> 4);
    int l = t & 15;
    int conv = blockIdx.y;
    if (node >= N) return;

    const size_t NB = (size_t)N * 64;
    const unsigned short* gm = g + (size_t)conv * NB;
    int rs = row_start[conv * N + node];
    int ne = cnt[conv * N + node];
    const int* sp = sorted + (size_t)conv * E + rs;

    ushort4 su = ((const ushort4*)(gm + (size_t)node * 64))[l];
    float4 acc = make_float4(bf2f(su.x), bf2f(su.y), bf2f(su.z), bf2f(su.w));

    for (int j = 0; j < ne; j++) {
        int s = sp[j];
        ushort4 u = ((const ushort4*)(gm + (size_t)s * 64))[l];
        acc.x += bf2f(u.x); acc.y += bf2f(u.y);
        acc.z += bf2f(u.z); acc.w += bf2f(u.w);
    }

    float dv = rsqrtf((float)(ne + 1));
    const float* bp = conv == 0 ? b1 : (conv == 1 ? b2 : b3);
    float4 bb = ((const float4*)bp)[l];
    float4 o = make_float4(acc.x * dv + bb.x, acc.y * dv + bb.y,
                           acc.z * dv + bb.z, acc.w * dv + bb.w);
    ((float4*)(out + (size_t)(1 + conv) * NB + (size_t)node * 64))[l] = o;
}

// ---------------- launch ----------------
extern "C" void kernel_launch(void* const* d_in, const int* in_sizes, int n_in,
                              void* d_out, int out_size, void* d_ws, size_t ws_size,
                              hipStream_t stream) {
    const float* x   = (const float*)d_in[0];
    const int*   e0  = (const int*)d_in[1];
    const int*   e1  = (const int*)d_in[2];
    const int*   e2  = (const int*)d_in[3];
    const float* Wln = (const float*)d_in[4];
    const float* bln = (const float*)d_in[5];
    const float* W1  = (const float*)d_in[6];
    const float* b1  = (const float*)d_in[7];
    const float* W2  = (const float*)d_in[8];
    const float* b2  = (const float*)d_in[9];
    const float* W3  = (const float*)d_in[10];
    const float* b3  = (const float*)d_in[11];

    int N = in_sizes[0] / 64;
    int E = in_sizes[1] / 2;
    int nbkt = (N + 255) >> 8;   // 391 for N=100000 (<= NBKT_MAX)
    float* out = (float*)d_out;

    // workspace carve (256B aligned)
    char* w = (char*)d_ws;
    auto alloc = [&](size_t bytes) {
        char* p = w;
        w += (bytes + 255) / 256 * 256;
        return p;
    };
    unsigned short* g      = (unsigned short*)alloc((size_t)3 * N * 64 * 2);
    int* cnt               = (int*)alloc((size_t)3 * N * 4);
    int* row_start         = (int*)alloc((size_t)3 * N * 4);
    int* sorted            = (int*)alloc((size_t)3 * E * 4);
    unsigned int* binned   = (unsigned int*)alloc((size_t)3 * E * 4);
    int* bucket_cnt        = (int*)alloc((size_t)3 * nbkt * 4);
    int* bucket_base       = (int*)alloc((size_t)3 * nbkt * 4);
    int* bucket_cursor     = (int*)alloc((size_t)3 * nbkt * 4);

    hipMemsetAsync(bucket_cnt, 0, (size_t)3 * nbkt * 4, stream);

    k_hist<<<dim3((E + 4095) / 4096, 3), 256, 0, stream>>>(e0, e1, e2, E, nbkt, bucket_cnt);
    k_scanb<<<dim3(1, 3), 512, 0, stream>>>(bucket_cnt, bucket_base, bucket_cursor, nbkt);
    k_bin<<<dim3((E + 8191) / 8192, 3), 256, 0, stream>>>(e0, e1, e2, E, nbkt, bucket_cursor, binned);
    k_csr<<<dim3(nbkt, 3), 256, 0, stream>>>(binned, bucket_cnt, bucket_base, E, N, nbkt,
                                             cnt, row_start, sorted);
    k_gemm<<<dim3((N + 255) / 256), 256, 0, stream>>>(x, Wln, bln, W1, W2, W3,
                                                      cnt, N, out, g);
    k_gather<<<dim3((N + 15) / 16, 3), 256, 0, stream>>>(g, sorted, row_start, cnt,
                                                         b1, b2, b3, N, E, out);
}

// Round 4
// 411.327 us; speedup vs baseline: 1.9930x; 1.2095x over previous
//
#include <hip/hip_runtime.h>
#include <hip/hip_bf16.h>

#define NBKT_MAX 512
#define BIN_CHUNK 8192
#define CSR_CAP 8192

// ---------------- helpers ----------------
__device__ __forceinline__ unsigned short f2bf(float f) {
    __hip_bfloat16 h = __float2bfloat16(f);
    union { __hip_bfloat16 h; unsigned short u; } cv; cv.h = h; return cv.u;
}
__device__ __forceinline__ float bf2f(unsigned short u) {
    unsigned int b = ((unsigned int)u) << 16;
    union { unsigned int u; float f; } cv; cv.u = b; return cv.f;
}
__device__ __forceinline__ const int* pick(const int* e0, const int* e1, const int* e2, int y) {
    return y == 0 ? e0 : (y == 1 ? e1 : e2);
}

// ---------------- 1. bucket histogram (bucket = dst >> 8) ----------------
__global__ __launch_bounds__(256) void k_hist(const int* __restrict__ e0, const int* __restrict__ e1,
                                              const int* __restrict__ e2, int E, int nbkt,
                                              int* __restrict__ bucket_cnt) {
    const int* ep = pick(e0, e1, e2, blockIdx.y);
    __shared__ int h[NBKT_MAX];
    for (int i = threadIdx.x; i < NBKT_MAX; i += 256) h[i] = 0;
    __syncthreads();
    int base = blockIdx.x * 4096;
    #pragma unroll
    for (int k = 0; k < 16; k++) {
        int i = base + k * 256 + threadIdx.x;
        if (i < E) atomicAdd(&h[ep[E + i] >> 8], 1);
    }
    __syncthreads();
    for (int i = threadIdx.x; i < nbkt; i += 256)
        if (h[i]) atomicAdd(&bucket_cnt[blockIdx.y * nbkt + i], h[i]);
}

// ---------------- 2. scan over buckets ----------------
__global__ __launch_bounds__(512) void k_scanb(const int* __restrict__ bucket_cnt,
                                               int* __restrict__ bucket_base,
                                               int* __restrict__ bucket_cursor, int nbkt) {
    __shared__ int s[512];
    int t = threadIdx.x;
    int v = (t < nbkt) ? bucket_cnt[blockIdx.y * nbkt + t] : 0;
    s[t] = v; __syncthreads();
    for (int off = 1; off < 512; off <<= 1) {
        int a = (t >= off) ? s[t - off] : 0;
        __syncthreads();
        s[t] += a;
        __syncthreads();
    }
    if (t < nbkt) {
        int e = s[t] - v;
        bucket_base[blockIdx.y * nbkt + t] = e;
        bucket_cursor[blockIdx.y * nbkt + t] = e;
    }
}

// ------- 3. multisplit binning with LDS reorder + coalesced copy-out -------
__global__ __launch_bounds__(256) void k_bin(const int* __restrict__ e0, const int* __restrict__ e1,
                                             const int* __restrict__ e2, int E, int nbkt,
                                             int* __restrict__ bucket_cursor,
                                             unsigned int* __restrict__ binned) {
    const int* ep = pick(e0, e1, e2, blockIdx.y);
    __shared__ int h[NBKT_MAX];       // counts -> cursor -> counts
    __shared__ int lbase[NBKT_MAX];   // scan buffer -> local exclusive base
    __shared__ int gbase[NBKT_MAX];   // global segment base
    __shared__ unsigned int stg[BIN_CHUNK];
    int t = threadIdx.x;
    h[t] = 0; h[t + 256] = 0;
    __syncthreads();
    int cbase = blockIdx.x * BIN_CHUNK;
    // phase 1: histogram
    #pragma unroll
    for (int k = 0; k < BIN_CHUNK / 256; k++) {
        int i = cbase + k * 256 + t;
        if (i < E) atomicAdd(&h[ep[E + i] >> 8], 1);
    }
    __syncthreads();
    // phase 2: scan (Hillis-Steele over 512 with 256 threads, 2 elems/thread)
    lbase[t] = h[t]; lbase[t + 256] = h[t + 256];
    __syncthreads();
    for (int off = 1; off < 512; off <<= 1) {
        int a0 = (t >= off) ? lbase[t - off] : 0;
        int i1 = t + 256;
        int a1 = (i1 >= off) ? lbase[i1 - off] : 0;
        __syncthreads();
        lbase[t] += a0; lbase[i1] += a1;
        __syncthreads();
    }
    // exclusive base + grab global cursor, reset h as local cursor
    int c0 = h[t], c1 = h[t + 256];
    int ex0 = lbase[t] - c0, ex1 = lbase[t + 256] - c1;
    if (t < nbkt && c0) gbase[t] = atomicAdd(&bucket_cursor[blockIdx.y * nbkt + t], c0);
    int i1g = t + 256;
    if (i1g < nbkt && c1) gbase[i1g] = atomicAdd(&bucket_cursor[blockIdx.y * nbkt + i1g], c1);
    __syncthreads();
    lbase[t] = ex0; lbase[t + 256] = ex1;
    h[t] = 0; h[t + 256] = 0;
    __syncthreads();
    // phase 3: place packed records into LDS staging (edges re-read, L2-hot)
    #pragma unroll
    for (int k = 0; k < BIN_CHUNK / 256; k++) {
        int i = cbase + k * 256 + t;
        if (i < E) {
            int s = ep[i];
            int d = ep[E + i];
            int b = d >> 8;
            int lp = atomicAdd(&h[b], 1);
            stg[lbase[b] + lp] = ((unsigned)s << 8) | (unsigned)(d & 255);
        }
    }
    __syncthreads();
    // phase 4: contiguous copy-out, 16-lane subgroup per bucket
    unsigned int* bout = binned + (size_t)blockIdx.y * E;
    int sg = t >> 4, lane = t & 15;
    for (int b = sg; b < nbkt; b += 16) {
        int n = h[b];
        if (!n) continue;
        int lb = lbase[b];
        unsigned int* dst = bout + gbase[b];
        for (int i = lane; i < n; i += 16) dst[i] = stg[lb + i];
    }
}

// ------- 4. per-bucket count + scan + CSR fill (LDS reorder, coalesced) ----
__global__ __launch_bounds__(256) void k_csr(const unsigned int* __restrict__ binned,
                                             const int* __restrict__ bucket_cnt,
                                             const int* __restrict__ bucket_base,
                                             int E, int N, int nbkt,
                                             int* __restrict__ cnt, int* __restrict__ row_start,
                                             int* __restrict__ sorted) {
    int b = blockIdx.x, conv = blockIdx.y, t = threadIdx.x;
    __shared__ int c[256];
    __shared__ int sc[256];
    __shared__ unsigned int stg[CSR_CAP];
    int segbase = bucket_base[conv * nbkt + b];
    int segcnt  = bucket_cnt[conv * nbkt + b];
    const unsigned int* bin = binned + (size_t)conv * E + segbase;

    c[t] = 0; __syncthreads();
    for (int i = t; i < segcnt; i += 256) atomicAdd(&c[bin[i] & 255], 1);
    __syncthreads();

    int v = c[t];
    sc[t] = v; __syncthreads();
    for (int off = 1; off < 256; off <<= 1) {
        int a = (t >= off) ? sc[t - off] : 0;
        __syncthreads();
        sc[t] += a;
        __syncthreads();
    }
    int ex = sc[t] - v;
    int node = (b << 8) + t;
    if (node < N) {
        cnt[conv * N + node] = v;
        row_start[conv * N + node] = segbase + ex;
    }
    __syncthreads();
    c[t] = ex;  // per-node cursor
    __syncthreads();
    int* so = sorted + (size_t)conv * E + segbase;
    if (segcnt <= CSR_CAP) {
        for (int i = t; i < segcnt; i += 256) {
            unsigned p = bin[i];
            int pos = atomicAdd(&c[p & 255], 1);
            stg[pos] = p >> 8;
        }
        __syncthreads();
        for (int i = t; i < segcnt; i += 256) so[i] = (int)stg[i];
    } else {
        for (int i = t; i < segcnt; i += 256) {
            unsigned p = bin[i];
            int pos = atomicAdd(&c[p & 255], 1);
            so[pos] = (int)(p >> 8);
        }
    }
}

// ---------------- 5. fused 4-matrix GEMM ----------------
#define GSTEP(XK, KC)                                                              \
    do {                                                                           \
        const float xk_ = (XK);                                                    \
        float4 w_;                                                                 \
        w_ = *(const float4*)(Wbase + 0 * 4096 + (KC) * 64);                       \
        a0.x += xk_ * w_.x; a0.y += xk_ * w_.y; a0.z += xk_ * w_.z; a0.w += xk_ * w_.w; \
        w_ = *(const float4*)(Wbase + 1 * 4096 + (KC) * 64);                       \
        a1.x += xk_ * w_.x; a1.y += xk_ * w_.y; a1.z += xk_ * w_.z; a1.w += xk_ * w_.w; \
        w_ = *(const float4*)(Wbase + 2 * 4096 + (KC) * 64);                       \
        a2.x += xk_ * w_.x; a2.y += xk_ * w_.y; a2.z += xk_ * w_.z; a2.w += xk_ * w_.w; \
        w_ = *(const float4*)(Wbase + 3 * 4096 + (KC) * 64);                       \
        a3.x += xk_ * w_.x; a3.y += xk_ * w_.y; a3.z += xk_ * w_.z; a3.w += xk_ * w_.w; \
    } while (0)

__global__ __launch_bounds__(256) void k_gemm(
    const float* __restrict__ x,
    const float* __restrict__ Wln, const float* __restrict__ bln,
    const float* __restrict__ W1, const float* __restrict__ W2,
    const float* __restrict__ W3,
    const int* __restrict__ cnt, int N,
    float* __restrict__ out0, unsigned short* __restrict__ g) {
    __shared__ float Wl[4 * 4096];
    int t = threadIdx.x;
    const float* Ws[4] = {Wln, W1, W2, W3};
    #pragma unroll
    for (int m = 0; m < 4; m++)
        for (int i = t; i < 4096; i += 256) Wl[m * 4096 + i] = Ws[m][i];
    __syncthreads();

    int r = blockIdx.x * 256 + t;
    if (r >= N) return;

    float4 xv[16];
    const float4* xr = (const float4*)(x + (size_t)r * 64);
    #pragma unroll
    for (int i = 0; i < 16; i++) xv[i] = xr[i];

    float dinv0 = rsqrtf((float)(cnt[0 * N + r] + 1));
    float dinv1 = rsqrtf((float)(cnt[1 * N + r] + 1));
    float dinv2 = rsqrtf((float)(cnt[2 * N + r] + 1));

    const size_t NB = (size_t)N * 64;
    float* orow = out0 + (size_t)r * 64;
    unsigned short* g0 = g + 0 * NB + (size_t)r * 64;
    unsigned short* g1 = g + 1 * NB + (size_t)r * 64;
    unsigned short* g2 = g + 2 * NB + (size_t)r * 64;

    for (int j4 = 0; j4 < 16; j4++) {
        float4 a0 = make_float4(0.f, 0.f, 0.f, 0.f), a1 = a0, a2 = a0, a3 = a0;
        const float* Wbase = Wl + j4 * 4;
        #pragma unroll
        for (int k4 = 0; k4 < 16; k4++) {
            const float4 xk4 = xv[k4];
            GSTEP(xk4.x, k4 * 4 + 0);
            GSTEP(xk4.y, k4 * 4 + 1);
            GSTEP(xk4.z, k4 * 4 + 2);
            GSTEP(xk4.w, k4 * 4 + 3);
        }
        float4 bl = ((const float4*)bln)[j4];
        float4 o = make_float4(a0.x + bl.x, a0.y + bl.y, a0.z + bl.z, a0.w + bl.w);
        ((float4*)orow)[j4] = o;
        ushort4 u;
        u.x = f2bf(a1.x * dinv0); u.y = f2bf(a1.y * dinv0);
        u.z = f2bf(a1.z * dinv0); u.w = f2bf(a1.w * dinv0);
        ((ushort4*)g0)[j4] = u;
        u.x = f2bf(a2.x * dinv1); u.y = f2bf(a2.y * dinv1);
        u.z = f2bf(a2.z * dinv1); u.w = f2bf(a2.w * dinv1);
        ((ushort4*)g1)[j4] = u;
        u.x = f2bf(a3.x * dinv2); u.y = f2bf(a3.y * dinv2);
        u.z = f2bf(a3.z * dinv2); u.w = f2bf(a3.w * dinv2);
        ((ushort4*)g2)[j4] = u;
    }
}

// ---------------- 6. gather + finalize (no atomics, unroll-4 MLP) ----------
__global__ __launch_bounds__(256) void k_gather(
    const unsigned short* __restrict__ g, const int* __restrict__ sorted,
    const int* __restrict__ row_start, const int* __restrict__ cnt,
    const float* __restrict__ b1, const float* __restrict__ b2,
    const float* __restrict__ b3,
    int N, int E, float* __restrict__ out) {
    int t = threadIdx.x;
    int node = blockIdx.x * 16 + (t >> 4);
    int l = t & 15;
    int conv = blockIdx.y;
    if (node >= N) return;

    const size_t NB = (size_t)N * 64;
    const unsigned short* gm = g + (size_t)conv * NB;
    int rs = row_start[conv * N + node];
    int ne = cnt[conv * N + node];
    const int* sp = sorted + (size_t)conv * E + rs;

    ushort4 su = ((const ushort4*)(gm + (size_t)node * 64))[l];
    float4 acc = make_float4(bf2f(su.x), bf2f(su.y), bf2f(su.z), bf2f(su.w));

    int j = 0;
    for (; j + 4 <= ne; j += 4) {
        int s0 = sp[j], s1 = sp[j + 1], s2 = sp[j + 2], s3 = sp[j + 3];
        ushort4 u0 = ((const ushort4*)(gm + (size_t)s0 * 64))[l];
        ushort4 u1 = ((const ushort4*)(gm + (size_t)s1 * 64))[l];
        ushort4 u2 = ((const ushort4*)(gm + (size_t)s2 * 64))[l];
        ushort4 u3 = ((const ushort4*)(gm + (size_t)s3 * 64))[l];
        acc.x += bf2f(u0.x) + bf2f(u1.x) + bf2f(u2.x) + bf2f(u3.x);
        acc.y += bf2f(u0.y) + bf2f(u1.y) + bf2f(u2.y) + bf2f(u3.y);
        acc.z += bf2f(u0.z) + bf2f(u1.z) + bf2f(u2.z) + bf2f(u3.z);
        acc.w += bf2f(u0.w) + bf2f(u1.w) + bf2f(u2.w) + bf2f(u3.w);
    }
    for (; j < ne; j++) {
        int s = sp[j];
        ushort4 u = ((const ushort4*)(gm + (size_t)s * 64))[l];
        acc.x += bf2f(u.x); acc.y += bf2f(u.y);
        acc.z += bf2f(u.z); acc.w += bf2f(u.w);
    }

    float dv = rsqrtf((float)(ne + 1));
    const float* bp = conv == 0 ? b1 : (conv == 1 ? b2 : b3);
    float4 bb = ((const float4*)bp)[l];
    float4 o = make_float4(acc.x * dv + bb.x, acc.y * dv + bb.y,
                           acc.z * dv + bb.z, acc.w * dv + bb.w);
    ((float4*)(out + (size_t)(1 + conv) * NB + (size_t)node * 64))[l] = o;
}

// ---------------- launch ----------------
extern "C" void kernel_launch(void* const* d_in, const int* in_sizes, int n_in,
                              void* d_out, int out_size, void* d_ws, size_t ws_size,
                              hipStream_t stream) {
    const float* x   = (const float*)d_in[0];
    const int*   e0  = (const int*)d_in[1];
    const int*   e1  = (const int*)d_in[2];
    const int*   e2  = (const int*)d_in[3];
    const float* Wln = (const float*)d_in[4];
    const float* bln = (const float*)d_in[5];
    const float* W1  = (const float*)d_in[6];
    const float* b1  = (const float*)d_in[7];
    const float* W2  = (const float*)d_in[8];
    const float* b2  = (const float*)d_in[9];
    const float* W3  = (const float*)d_in[10];
    const float* b3  = (const float*)d_in[11];

    int N = in_sizes[0] / 64;
    int E = in_sizes[1] / 2;
    int nbkt = (N + 255) >> 8;   // 391 for N=100000 (<= NBKT_MAX)
    float* out = (float*)d_out;

    // workspace carve (256B aligned)
    char* w = (char*)d_ws;
    auto alloc = [&](size_t bytes) {
        char* p = w;
        w += (bytes + 255) / 256 * 256;
        return p;
    };
    unsigned short* g      = (unsigned short*)alloc((size_t)3 * N * 64 * 2);
    int* cnt               = (int*)alloc((size_t)3 * N * 4);
    int* row_start         = (int*)alloc((size_t)3 * N * 4);
    int* sorted            = (int*)alloc((size_t)3 * E * 4);
    unsigned int* binned   = (unsigned int*)alloc((size_t)3 * E * 4);
    int* bucket_cnt        = (int*)alloc((size_t)3 * nbkt * 4);
    int* bucket_base       = (int*)alloc((size_t)3 * nbkt * 4);
    int* bucket_cursor     = (int*)alloc((size_t)3 * nbkt * 4);

    hipMemsetAsync(bucket_cnt, 0, (size_t)3 * nbkt * 4, stream);

    k_hist<<<dim3((E + 4095) / 4096, 3), 256, 0, stream>>>(e0, e1, e2, E, nbkt, bucket_cnt);
    k_scanb<<<dim3(1, 3), 512, 0, stream>>>(bucket_cnt, bucket_base, bucket_cursor, nbkt);
    k_bin<<<dim3((E + BIN_CHUNK - 1) / BIN_CHUNK, 3), 256, 0, stream>>>(e0, e1, e2, E, nbkt,
                                                                        bucket_cursor, binned);
    k_csr<<<dim3(nbkt, 3), 256, 0, stream>>>(binned, bucket_cnt, bucket_base, E, N, nbkt,
                                             cnt, row_start, sorted);
    k_gemm<<<dim3((N + 255) / 256), 256, 0, stream>>>(x, Wln, bln, W1, W2, W3,
                                                      cnt, N, out, g);
    k_gather<<<dim3((N + 15) / 16, 3), 256, 0, stream>>>(g, sorted, row_start, cnt,
                                                         b1, b2, b3, N, E, out);
}

// Round 5
// 396.067 us; speedup vs baseline: 2.0698x; 1.0385x over previous
//
#include <hip/hip_runtime.h>
#include <hip/hip_bf16.h>

#define NBKT_MAX 512
#define BIN_CHUNK 8192
#define CSR_CAP 8192
#define GR 256   // gemm rows per block tile

// ---------------- helpers ----------------
__device__ __forceinline__ unsigned short f2bf(float f) {
    __hip_bfloat16 h = __float2bfloat16(f);
    union { __hip_bfloat16 h; unsigned short u; } cv; cv.h = h; return cv.u;
}
__device__ __forceinline__ float bf2f(unsigned short u) {
    unsigned int b = ((unsigned int)u) << 16;
    union { unsigned int u; float f; } cv; cv.u = b; return cv.f;
}
__device__ __forceinline__ const int* pick(const int* e0, const int* e1, const int* e2, int y) {
    return y == 0 ? e0 : (y == 1 ? e1 : e2);
}

// ---------------- 1. bucket histogram (bucket = dst >> 8) ----------------
__global__ __launch_bounds__(256) void k_hist(const int* __restrict__ e0, const int* __restrict__ e1,
                                              const int* __restrict__ e2, int E, int nbkt,
                                              int* __restrict__ bucket_cnt) {
    const int* ep = pick(e0, e1, e2, blockIdx.y);
    __shared__ int h[NBKT_MAX];
    for (int i = threadIdx.x; i < NBKT_MAX; i += 256) h[i] = 0;
    __syncthreads();
    int base = blockIdx.x * 4096;
    #pragma unroll
    for (int k = 0; k < 16; k++) {
        int i = base + k * 256 + threadIdx.x;
        if (i < E) atomicAdd(&h[ep[E + i] >> 8], 1);
    }
    __syncthreads();
    for (int i = threadIdx.x; i < nbkt; i += 256)
        if (h[i]) atomicAdd(&bucket_cnt[blockIdx.y * nbkt + i], h[i]);
}

// ---------------- 2. scan over buckets ----------------
__global__ __launch_bounds__(512) void k_scanb(const int* __restrict__ bucket_cnt,
                                               int* __restrict__ bucket_base,
                                               int* __restrict__ bucket_cursor, int nbkt) {
    __shared__ int s[512];
    int t = threadIdx.x;
    int v = (t < nbkt) ? bucket_cnt[blockIdx.y * nbkt + t] : 0;
    s[t] = v; __syncthreads();
    for (int off = 1; off < 512; off <<= 1) {
        int a = (t >= off) ? s[t - off] : 0;
        __syncthreads();
        s[t] += a;
        __syncthreads();
    }
    if (t < nbkt) {
        int e = s[t] - v;
        bucket_base[blockIdx.y * nbkt + t] = e;
        bucket_cursor[blockIdx.y * nbkt + t] = e;
    }
}

// ------- 3. multisplit binning with LDS reorder + coalesced copy-out -------
__global__ __launch_bounds__(256) void k_bin(const int* __restrict__ e0, const int* __restrict__ e1,
                                             const int* __restrict__ e2, int E, int nbkt,
                                             int* __restrict__ bucket_cursor,
                                             unsigned int* __restrict__ binned) {
    const int* ep = pick(e0, e1, e2, blockIdx.y);
    __shared__ int h[NBKT_MAX];       // counts -> cursor -> counts
    __shared__ int lbase[NBKT_MAX];   // scan buffer -> local exclusive base
    __shared__ int gbase[NBKT_MAX];   // global segment base
    __shared__ unsigned int stg[BIN_CHUNK];
    int t = threadIdx.x;
    h[t] = 0; h[t + 256] = 0;
    __syncthreads();
    int cbase = blockIdx.x * BIN_CHUNK;
    // phase 1: histogram
    #pragma unroll
    for (int k = 0; k < BIN_CHUNK / 256; k++) {
        int i = cbase + k * 256 + t;
        if (i < E) atomicAdd(&h[ep[E + i] >> 8], 1);
    }
    __syncthreads();
    // phase 2: scan (Hillis-Steele over 512 with 256 threads, 2 elems/thread)
    lbase[t] = h[t]; lbase[t + 256] = h[t + 256];
    __syncthreads();
    for (int off = 1; off < 512; off <<= 1) {
        int a0 = (t >= off) ? lbase[t - off] : 0;
        int i1 = t + 256;
        int a1 = (i1 >= off) ? lbase[i1 - off] : 0;
        __syncthreads();
        lbase[t] += a0; lbase[i1] += a1;
        __syncthreads();
    }
    // exclusive base + grab global cursor, reset h as local cursor
    int c0 = h[t], c1 = h[t + 256];
    int ex0 = lbase[t] - c0, ex1 = lbase[t + 256] - c1;
    if (t < nbkt && c0) gbase[t] = atomicAdd(&bucket_cursor[blockIdx.y * nbkt + t], c0);
    int i1g = t + 256;
    if (i1g < nbkt && c1) gbase[i1g] = atomicAdd(&bucket_cursor[blockIdx.y * nbkt + i1g], c1);
    __syncthreads();
    lbase[t] = ex0; lbase[t + 256] = ex1;
    h[t] = 0; h[t + 256] = 0;
    __syncthreads();
    // phase 3: place packed records into LDS staging (edges re-read, L2-hot)
    #pragma unroll
    for (int k = 0; k < BIN_CHUNK / 256; k++) {
        int i = cbase + k * 256 + t;
        if (i < E) {
            int s = ep[i];
            int d = ep[E + i];
            int b = d >> 8;
            int lp = atomicAdd(&h[b], 1);
            stg[lbase[b] + lp] = ((unsigned)s << 8) | (unsigned)(d & 255);
        }
    }
    __syncthreads();
    // phase 4: contiguous copy-out, 16-lane subgroup per bucket
    unsigned int* bout = binned + (size_t)blockIdx.y * E;
    int sg = t >> 4, lane = t & 15;
    for (int b = sg; b < nbkt; b += 16) {
        int n = h[b];
        if (!n) continue;
        int lb = lbase[b];
        unsigned int* dst = bout + gbase[b];
        for (int i = lane; i < n; i += 16) dst[i] = stg[lb + i];
    }
}

// ------- 4. per-bucket count + scan + CSR fill (LDS reorder, coalesced) ----
__global__ __launch_bounds__(256) void k_csr(const unsigned int* __restrict__ binned,
                                             const int* __restrict__ bucket_cnt,
                                             const int* __restrict__ bucket_base,
                                             int E, int N, int nbkt,
                                             int* __restrict__ cnt, int* __restrict__ row_start,
                                             int* __restrict__ sorted) {
    int b = blockIdx.x, conv = blockIdx.y, t = threadIdx.x;
    __shared__ int c[256];
    __shared__ int sc[256];
    __shared__ unsigned int stg[CSR_CAP];
    int segbase = bucket_base[conv * nbkt + b];
    int segcnt  = bucket_cnt[conv * nbkt + b];
    const unsigned int* bin = binned + (size_t)conv * E + segbase;

    c[t] = 0; __syncthreads();
    for (int i = t; i < segcnt; i += 256) atomicAdd(&c[bin[i] & 255], 1);
    __syncthreads();

    int v = c[t];
    sc[t] = v; __syncthreads();
    for (int off = 1; off < 256; off <<= 1) {
        int a = (t >= off) ? sc[t - off] : 0;
        __syncthreads();
        sc[t] += a;
        __syncthreads();
    }
    int ex = sc[t] - v;
    int node = (b << 8) + t;
    if (node < N) {
        cnt[conv * N + node] = v;
        row_start[conv * N + node] = segbase + ex;
    }
    __syncthreads();
    c[t] = ex;  // per-node cursor
    __syncthreads();
    int* so = sorted + (size_t)conv * E + segbase;
    if (segcnt <= CSR_CAP) {
        for (int i = t; i < segcnt; i += 256) {
            unsigned p = bin[i];
            int pos = atomicAdd(&c[p & 255], 1);
            stg[pos] = p >> 8;
        }
        __syncthreads();
        for (int i = t; i < segcnt; i += 256) so[i] = (int)stg[i];
    } else {
        for (int i = t; i < segcnt; i += 256) {
            unsigned p = bin[i];
            int pos = atomicAdd(&c[p & 255], 1);
            so[pos] = (int)(p >> 8);
        }
    }
}

// ---------------- 5. fused 4-matrix GEMM (W-in-registers, x-broadcast) -----
// 8 waves/block; wave = (wi, pair): pair 0 -> {Wln -> out0, W1 -> g0},
// pair 1 -> {W2 -> g1, W3 -> g2}. Lane l owns output column l.
// Stores are full-line contiguous (256 B fp32 / 128 B bf16 per wave-store).
__global__ __launch_bounds__(512) void k_gemm(
    const float* __restrict__ x,
    const float* __restrict__ Wln, const float* __restrict__ bln,
    const float* __restrict__ W1, const float* __restrict__ W2,
    const float* __restrict__ W3,
    const int* __restrict__ cnt, int N,
    float* __restrict__ out0, unsigned short* __restrict__ g) {
    __shared__ float xs[GR * 64];   // 64 KB x tile
    int t = threadIdx.x;
    int base = blockIdx.x * GR;
    int rows = min(GR, N - base);

    // coalesced x-tile load
    {
        int nv = rows * 16;
        const float4* xg = (const float4*)(x + (size_t)base * 64);
        float4* xsv = (float4*)xs;
        for (int i = t; i < nv; i += 512) xsv[i] = xg[i];
    }

    int w = t >> 6;
    int lane = t & 63;
    int pair = w & 1;
    int wi = w >> 1;

    // W columns into registers (lane l holds column l of both matrices)
    const float* WA = pair == 0 ? Wln : W2;
    const float* WB = pair == 0 ? W1 : W3;
    float wa[64], wb[64];
    #pragma unroll
    for (int k = 0; k < 64; k++) {
        wa[k] = WA[k * 64 + lane];
        wb[k] = WB[k * 64 + lane];
    }
    float bl = (pair == 0) ? bln[lane] : 0.f;
    __syncthreads();

    const size_t NB = (size_t)N * 64;
    int r0 = wi * (GR / 4);
    int r1 = min(r0 + GR / 4, rows);
    for (int r = r0; r < r1; r++) {
        const float4* xr = (const float4*)(xs + r * 64);
        float accA = 0.f, accB = 0.f;
        #pragma unroll
        for (int k4 = 0; k4 < 16; k4++) {
            float4 xv = xr[k4];   // lane-uniform address: LDS broadcast
            accA += xv.x * wa[k4 * 4 + 0]; accB += xv.x * wb[k4 * 4 + 0];
            accA += xv.y * wa[k4 * 4 + 1]; accB += xv.y * wb[k4 * 4 + 1];
            accA += xv.z * wa[k4 * 4 + 2]; accB += xv.z * wb[k4 * 4 + 2];
            accA += xv.w * wa[k4 * 4 + 3]; accB += xv.w * wb[k4 * 4 + 3];
        }
        int gr = base + r;
        if (pair == 0) {
            out0[(size_t)gr * 64 + lane] = accA + bl;
            float d0 = rsqrtf((float)(cnt[gr] + 1));
            g[(size_t)gr * 64 + lane] = f2bf(accB * d0);
        } else {
            float d1 = rsqrtf((float)(cnt[N + gr] + 1));
            float d2 = rsqrtf((float)(cnt[2 * N + gr] + 1));
            g[NB + (size_t)gr * 64 + lane] = f2bf(accA * d1);
            g[2 * NB + (size_t)gr * 64 + lane] = f2bf(accB * d2);
        }
    }
}

// ---------------- 6. gather + finalize (no atomics, unroll-4 MLP) ----------
__global__ __launch_bounds__(256) void k_gather(
    const unsigned short* __restrict__ g, const int* __restrict__ sorted,
    const int* __restrict__ row_start, const int* __restrict__ cnt,
    const float* __restrict__ b1, const float* __restrict__ b2,
    const float* __restrict__ b3,
    int N, int E, float* __restrict__ out) {
    int t = threadIdx.x;
    int node = blockIdx.x * 16 + (t >> 4);
    int l = t & 15;
    int conv = blockIdx.y;
    if (node >= N) return;

    const size_t NB = (size_t)N * 64;
    const unsigned short* gm = g + (size_t)conv * NB;
    int rs = row_start[conv * N + node];
    int ne = cnt[conv * N + node];
    const int* sp = sorted + (size_t)conv * E + rs;

    ushort4 su = ((const ushort4*)(gm + (size_t)node * 64))[l];
    float4 acc = make_float4(bf2f(su.x), bf2f(su.y), bf2f(su.z), bf2f(su.w));

    int j = 0;
    for (; j + 4 <= ne; j += 4) {
        int s0 = sp[j], s1 = sp[j + 1], s2 = sp[j + 2], s3 = sp[j + 3];
        ushort4 u0 = ((const ushort4*)(gm + (size_t)s0 * 64))[l];
        ushort4 u1 = ((const ushort4*)(gm + (size_t)s1 * 64))[l];
        ushort4 u2 = ((const ushort4*)(gm + (size_t)s2 * 64))[l];
        ushort4 u3 = ((const ushort4*)(gm + (size_t)s3 * 64))[l];
        acc.x += bf2f(u0.x) + bf2f(u1.x) + bf2f(u2.x) + bf2f(u3.x);
        acc.y += bf2f(u0.y) + bf2f(u1.y) + bf2f(u2.y) + bf2f(u3.y);
        acc.z += bf2f(u0.z) + bf2f(u1.z) + bf2f(u2.z) + bf2f(u3.z);
        acc.w += bf2f(u0.w) + bf2f(u1.w) + bf2f(u2.w) + bf2f(u3.w);
    }
    for (; j < ne; j++) {
        int s = sp[j];
        ushort4 u = ((const ushort4*)(gm + (size_t)s * 64))[l];
        acc.x += bf2f(u.x); acc.y += bf2f(u.y);
        acc.z += bf2f(u.z); acc.w += bf2f(u.w);
    }

    float dv = rsqrtf((float)(ne + 1));
    const float* bp = conv == 0 ? b1 : (conv == 1 ? b2 : b3);
    float4 bb = ((const float4*)bp)[l];
    float4 o = make_float4(acc.x * dv + bb.x, acc.y * dv + bb.y,
                           acc.z * dv + bb.z, acc.w * dv + bb.w);
    ((float4*)(out + (size_t)(1 + conv) * NB + (size_t)node * 64))[l] = o;
}

// ---------------- launch ----------------
extern "C" void kernel_launch(void* const* d_in, const int* in_sizes, int n_in,
                              void* d_out, int out_size, void* d_ws, size_t ws_size,
                              hipStream_t stream) {
    const float* x   = (const float*)d_in[0];
    const int*   e0  = (const int*)d_in[1];
    const int*   e1  = (const int*)d_in[2];
    const int*   e2  = (const int*)d_in[3];
    const float* Wln = (const float*)d_in[4];
    const float* bln = (const float*)d_in[5];
    const float* W1  = (const float*)d_in[6];
    const float* b1  = (const float*)d_in[7];
    const float* W2  = (const float*)d_in[8];
    const float* b2  = (const float*)d_in[9];
    const float* W3  = (const float*)d_in[10];
    const float* b3  = (const float*)d_in[11];

    int N = in_sizes[0] / 64;
    int E = in_sizes[1] / 2;
    int nbkt = (N + 255) >> 8;   // 391 for N=100000 (<= NBKT_MAX)
    float* out = (float*)d_out;

    // workspace carve (256B aligned)
    char* w = (char*)d_ws;
    auto alloc = [&](size_t bytes) {
        char* p = w;
        w += (bytes + 255) / 256 * 256;
        return p;
    };
    unsigned short* g      = (unsigned short*)alloc((size_t)3 * N * 64 * 2);
    int* cnt               = (int*)alloc((size_t)3 * N * 4);
    int* row_start         = (int*)alloc((size_t)3 * N * 4);
    int* sorted            = (int*)alloc((size_t)3 * E * 4);
    unsigned int* binned   = (unsigned int*)alloc((size_t)3 * E * 4);
    int* bucket_cnt        = (int*)alloc((size_t)3 * nbkt * 4);
    int* bucket_base       = (int*)alloc((size_t)3 * nbkt * 4);
    int* bucket_cursor     = (int*)alloc((size_t)3 * nbkt * 4);

    hipMemsetAsync(bucket_cnt, 0, (size_t)3 * nbkt * 4, stream);

    k_hist<<<dim3((E + 4095) / 4096, 3), 256, 0, stream>>>(e0, e1, e2, E, nbkt, bucket_cnt);
    k_scanb<<<dim3(1, 3), 512, 0, stream>>>(bucket_cnt, bucket_base, bucket_cursor, nbkt);
    k_bin<<<dim3((E + BIN_CHUNK - 1) / BIN_CHUNK, 3), 256, 0, stream>>>(e0, e1, e2, E, nbkt,
                                                                        bucket_cursor, binned);
    k_csr<<<dim3(nbkt, 3), 256, 0, stream>>>(binned, bucket_cnt, bucket_base, E, N, nbkt,
                                             cnt, row_start, sorted);
    k_gemm<<<dim3((N + GR - 1) / GR), 512, 0, stream>>>(x, Wln, bln, W1, W2, W3,
                                                        cnt, N, out, g);
    k_gather<<<dim3((N + 15) / 16, 3), 256, 0, stream>>>(g, sorted, row_start, cnt,
                                                         b1, b2, b3, N, E, out);
}